// Round 1
// baseline (255.661 us; speedup 1.0000x reference)
//
#include <hip/hip_runtime.h>

// ---------------------------------------------------------------------------
// Causal MHA block: QKV proj (bf16 MFMA) -> flash attention -> out proj.
// B=2, S=2048, E=1024, H=16, D=64.  All matmuls bf16 16x16x32 MFMA, fp32 acc.
// Workspace usage: ~42 MB (assumes ws_size >= 42 MB).
// ---------------------------------------------------------------------------

#define EMB 1024
#define SEQ 2048
#define NB 2
#define NH 16
#define HD 64

typedef float f32x4 __attribute__((ext_vector_type(4)));
typedef float floatx4 __attribute__((ext_vector_type(4)));
typedef short short8 __attribute__((ext_vector_type(8)));
typedef __bf16 bf16x8 __attribute__((ext_vector_type(8)));
typedef unsigned short ushortx4 __attribute__((ext_vector_type(4)));

__device__ __forceinline__ unsigned short f2bf(float f) {
  unsigned u = __builtin_bit_cast(unsigned, f);
  u += 0x7fffu + ((u >> 16) & 1u);   // round-to-nearest-even
  return (unsigned short)(u >> 16);
}

__device__ __forceinline__ f32x4 mfma16(short8 a, short8 b, f32x4 c) {
  return __builtin_amdgcn_mfma_f32_16x16x32_bf16(
      __builtin_bit_cast(bf16x8, a), __builtin_bit_cast(bf16x8, b), c, 0, 0, 0);
}

// async global -> LDS, 16B per lane; lds dest is wave-uniform base + lane*16
__device__ __forceinline__ void gload16(const void* g, void* lds) {
  __builtin_amdgcn_global_load_lds(
      (const __attribute__((address_space(1))) unsigned int*)g,
      (__attribute__((address_space(3))) unsigned int*)lds, 16, 0, 0);
}

// ---------------------------------------------------------------------------
// fp32 -> bf16 convert (x)
// ---------------------------------------------------------------------------
__global__ __launch_bounds__(256) void cvt_x_kernel(
    const float* __restrict__ x, unsigned short* __restrict__ out) {
  const int idx = (blockIdx.x * 256 + threadIdx.x) * 4;
  floatx4 v = *(const floatx4*)(x + idx);
  ushortx4 o;
  #pragma unroll
  for (int i = 0; i < 4; ++i) o[i] = f2bf(v[i]);
  *(ushortx4*)(out + idx) = o;
}

// ---------------------------------------------------------------------------
// fp32 W[k][n] -> bf16 WT[n][k]  (convert + transpose, 32x32 LDS tile)
// ---------------------------------------------------------------------------
__global__ __launch_bounds__(256) void cvt_wt_kernel(
    const float* __restrict__ W, unsigned short* __restrict__ WT) {
  __shared__ unsigned short tile[32][33];
  const int k0 = blockIdx.x * 32, n0 = blockIdx.y * 32;
  const int t = threadIdx.x;
  const int r = t >> 3, c = (t & 7) * 4;
  floatx4 v = *(const floatx4*)(W + (k0 + r) * EMB + n0 + c);
  #pragma unroll
  for (int i = 0; i < 4; ++i) tile[r][c + i] = f2bf(v[i]);
  __syncthreads();
  ushortx4 o;
  #pragma unroll
  for (int i = 0; i < 4; ++i) o[i] = tile[c + i][r];
  *(ushortx4*)(WT + (n0 + r) * EMB + k0 + c) = o;
}

// ---------------------------------------------------------------------------
// GEMM: C[m][n] = Xb[m][k] * WT[n][k]^T + bias.  128x128 tile, BK=64, 4 waves.
// z=0 -> Q[b][h][s][d], z=1 -> K[b][h][s][d], z=2 -> Vt[b][h][d][s]
// ---------------------------------------------------------------------------
__global__ __launch_bounds__(256) void gemm_qkv_kernel(
    const unsigned short* __restrict__ Xb,
    const unsigned short* __restrict__ W0, const unsigned short* __restrict__ W1,
    const unsigned short* __restrict__ W2,
    const float* __restrict__ b0, const float* __restrict__ b1,
    const float* __restrict__ b2,
    unsigned short* __restrict__ Qo, unsigned short* __restrict__ Ko,
    unsigned short* __restrict__ Vo) {
  __shared__ __align__(16) unsigned short As[128 * 64];
  __shared__ __align__(16) unsigned short Bs[128 * 64];
  const int z = blockIdx.z;
  const unsigned short* Wt = (z == 0) ? W0 : ((z == 1) ? W1 : W2);
  const float* bias = (z == 0) ? b0 : ((z == 1) ? b1 : b2);
  const int m0 = blockIdx.y * 128, n0 = blockIdx.x * 128;
  const int tid = threadIdx.x, l = tid & 63, w = tid >> 6;
  const int g = l >> 4, ln = l & 15;
  const int wr = w >> 1, wc = w & 1;

  f32x4 acc[4][4];
  #pragma unroll
  for (int i = 0; i < 4; ++i)
    #pragma unroll
    for (int j = 0; j < 4; ++j) acc[i][j] = (f32x4){0.f, 0.f, 0.f, 0.f};

  for (int kt = 0; kt < 16; ++kt) {
    const int kb = kt * 64;
    #pragma unroll
    for (int it = 0; it < 4; ++it) {
      const int chunk = w * 4 + it;          // 0..15, 1KB each
      const int lin = chunk * 64 + l;        // 16B-chunk index 0..1023
      const int row = lin >> 3, col = (lin & 7) * 8;
      gload16(Xb + (m0 + row) * EMB + kb + col, (char*)As + chunk * 1024);
      gload16(Wt + (n0 + row) * EMB + kb + col, (char*)Bs + chunk * 1024);
    }
    __syncthreads();
    #pragma unroll
    for (int kk = 0; kk < 64; kk += 32) {
      short8 a[4], b[4];
      #pragma unroll
      for (int i = 0; i < 4; ++i)
        a[i] = *(const short8*)(As + (wr * 64 + i * 16 + ln) * 64 + kk + g * 8);
      #pragma unroll
      for (int j = 0; j < 4; ++j)
        b[j] = *(const short8*)(Bs + (wc * 64 + j * 16 + ln) * 64 + kk + g * 8);
      #pragma unroll
      for (int i = 0; i < 4; ++i)
        #pragma unroll
        for (int j = 0; j < 4; ++j)
          acc[i][j] = mfma16(a[i], b[j], acc[i][j]);
    }
    __syncthreads();
  }

  const int mb = m0 + wr * 64, nb = n0 + wc * 64;
  #pragma unroll
  for (int j = 0; j < 4; ++j) {
    const int n = nb + j * 16 + ln;
    const float bgain = bias[n];
    const int h = n >> 6, d = n & 63;
    #pragma unroll
    for (int i = 0; i < 4; ++i) {
      const int mf = mb + i * 16 + 4 * g;    // first of 4 consecutive m rows
      const int bb = mf >> 11, ss = mf & 2047;
      if (z == 2) {
        ushortx4 o;
        #pragma unroll
        for (int e = 0; e < 4; ++e) o[e] = f2bf(acc[i][j][e] + bgain);
        *(ushortx4*)(Vo + ((bb * NH + h) * HD + d) * SEQ + ss) = o;
      } else {
        unsigned short* dst = (z == 0) ? Qo : Ko;
        const int base = ((bb * NH + h) * SEQ + ss) * HD + d;
        #pragma unroll
        for (int e = 0; e < 4; ++e) dst[base + e * HD] = f2bf(acc[i][j][e] + bgain);
      }
    }
  }
}

// ---------------------------------------------------------------------------
// Causal flash attention.  Block = 4 waves, q-tile 64 (16 rows/wave), kv-tile 64.
// Q,K: [b][h][s][d] bf16;  Vt: [b][h][d][s] bf16;  O: [b][s][h*64+d] bf16.
// ---------------------------------------------------------------------------
__global__ __launch_bounds__(256) void attn_kernel(
    const unsigned short* __restrict__ Q, const unsigned short* __restrict__ K,
    const unsigned short* __restrict__ Vt, unsigned short* __restrict__ O) {
  __shared__ __align__(16) unsigned short Kt[64 * 64];
  __shared__ __align__(16) unsigned short Vl[64 * 64];
  __shared__ __align__(16) unsigned short Pl[4][16 * 64];
  const int qt = blockIdx.x, h = blockIdx.y, b = blockIdx.z;
  const int tid = threadIdx.x, l = tid & 63, w = tid >> 6;
  const int g = l >> 4, ln = l & 15;
  const int bh = b * NH + h;
  const int baseQK = bh * SEQ * HD;   // [s][d]
  const int baseV = bh * HD * SEQ;    // [d][s]
  const int q0 = qt * 64;
  const int qw = q0 + w * 16;

  short8 qf[2];
  {
    const int qrow = qw + ln;
    qf[0] = *(const short8*)(Q + baseQK + qrow * HD + g * 8);
    qf[1] = *(const short8*)(Q + baseQK + qrow * HD + 32 + g * 8);
  }
  f32x4 acc[4];
  float m_run[4], l_run[4];
  #pragma unroll
  for (int e = 0; e < 4; ++e) { m_run[e] = -1e30f; l_run[e] = 0.f; }
  #pragma unroll
  for (int dj = 0; dj < 4; ++dj) acc[dj] = (f32x4){0.f, 0.f, 0.f, 0.f};

  for (int kt = 0; kt <= qt; ++kt) {
    #pragma unroll
    for (int it = 0; it < 2; ++it) {
      const int chunk = w * 2 + it;          // 0..7
      const int lin = chunk * 64 + l;        // 0..511
      const int row = lin >> 3, col = (lin & 7) * 8;
      gload16(K + baseQK + (kt * 64 + row) * HD + col, (char*)Kt + chunk * 1024);
      gload16(Vt + baseV + row * SEQ + kt * 64 + col, (char*)Vl + chunk * 1024);
    }
    __syncthreads();

    const bool diag = (kt == qt);
    f32x4 sv[4];
    #pragma unroll
    for (int j = 0; j < 4; ++j) {
      if (diag && j > w) {                    // fully masked fragment
        sv[j] = (f32x4){-1e30f, -1e30f, -1e30f, -1e30f};
        continue;
      }
      f32x4 t = (f32x4){0.f, 0.f, 0.f, 0.f};
      #pragma unroll
      for (int kd = 0; kd < 2; ++kd) {
        short8 kf = *(const short8*)(Kt + (j * 16 + ln) * 64 + kd * 32 + g * 8);
        t = mfma16(qf[kd], kf, t);
      }
      if (!diag) {
        #pragma unroll
        for (int e = 0; e < 4; ++e) sv[j][e] = t[e] * 0.125f;
      } else {
        const int kglob = kt * 64 + j * 16 + ln;
        #pragma unroll
        for (int e = 0; e < 4; ++e) {
          const int qglob = qw + 4 * g + e;
          sv[j][e] = (kglob <= qglob) ? t[e] * 0.125f : -1e30f;
        }
      }
    }

    // wave-parallel online softmax (rows live on 16-lane column groups)
    float tm[4], al[4], rs[4];
    #pragma unroll
    for (int e = 0; e < 4; ++e) {
      float v0 = fmaxf(fmaxf(sv[0][e], sv[1][e]), fmaxf(sv[2][e], sv[3][e]));
      v0 = fmaxf(v0, __shfl_xor(v0, 1));
      v0 = fmaxf(v0, __shfl_xor(v0, 2));
      v0 = fmaxf(v0, __shfl_xor(v0, 4));
      v0 = fmaxf(v0, __shfl_xor(v0, 8));
      tm[e] = v0;
    }
    #pragma unroll
    for (int e = 0; e < 4; ++e) {
      const float nm = fmaxf(m_run[e], tm[e]);
      al[e] = __expf(m_run[e] - nm);
      m_run[e] = nm;
      rs[e] = 0.f;
    }
    #pragma unroll
    for (int j = 0; j < 4; ++j) {
      #pragma unroll
      for (int e = 0; e < 4; ++e) {
        const float p = __expf(sv[j][e] - m_run[e]);
        rs[e] += p;
        Pl[w][(4 * g + e) * 64 + j * 16 + ln] = f2bf(p);
      }
    }
    #pragma unroll
    for (int e = 0; e < 4; ++e) {
      float r = rs[e];
      r += __shfl_xor(r, 1);
      r += __shfl_xor(r, 2);
      r += __shfl_xor(r, 4);
      r += __shfl_xor(r, 8);
      l_run[e] = l_run[e] * al[e] + r;
    }
    #pragma unroll
    for (int dj = 0; dj < 4; ++dj)
      #pragma unroll
      for (int e = 0; e < 4; ++e) acc[dj][e] *= al[e];

    const int ksmax = (diag && w < 2) ? 1 : 2;  // skip all-zero P half-tiles
    #pragma unroll
    for (int dj = 0; dj < 4; ++dj) {
      for (int ks = 0; ks < ksmax; ++ks) {
        short8 pa = *(const short8*)(&Pl[w][ln * 64 + ks * 32 + g * 8]);
        short8 vb = *(const short8*)(Vl + (dj * 16 + ln) * 64 + ks * 32 + g * 8);
        acc[dj] = mfma16(pa, vb, acc[dj]);
      }
    }
    __syncthreads();
  }

  #pragma unroll
  for (int e = 0; e < 4; ++e) l_run[e] = 1.f / l_run[e];
  #pragma unroll
  for (int dj = 0; dj < 4; ++dj) {
    #pragma unroll
    for (int e = 0; e < 4; ++e) {
      const int s = qw + 4 * g + e;
      O[(b * SEQ + s) * EMB + h * HD + dj * 16 + ln] = f2bf(acc[dj][e] * l_run[e]);
    }
  }
}

// ---------------------------------------------------------------------------
// Output projection: fp32 out = AttnOut(bf16) @ Wo + bo
// ---------------------------------------------------------------------------
__global__ __launch_bounds__(256) void gemm_o_kernel(
    const unsigned short* __restrict__ Ab, const unsigned short* __restrict__ Wt,
    const float* __restrict__ bias, float* __restrict__ out) {
  __shared__ __align__(16) unsigned short As[128 * 64];
  __shared__ __align__(16) unsigned short Bs[128 * 64];
  const int m0 = blockIdx.y * 128, n0 = blockIdx.x * 128;
  const int tid = threadIdx.x, l = tid & 63, w = tid >> 6;
  const int g = l >> 4, ln = l & 15;
  const int wr = w >> 1, wc = w & 1;

  f32x4 acc[4][4];
  #pragma unroll
  for (int i = 0; i < 4; ++i)
    #pragma unroll
    for (int j = 0; j < 4; ++j) acc[i][j] = (f32x4){0.f, 0.f, 0.f, 0.f};

  for (int kt = 0; kt < 16; ++kt) {
    const int kb = kt * 64;
    #pragma unroll
    for (int it = 0; it < 4; ++it) {
      const int chunk = w * 4 + it;
      const int lin = chunk * 64 + l;
      const int row = lin >> 3, col = (lin & 7) * 8;
      gload16(Ab + (m0 + row) * EMB + kb + col, (char*)As + chunk * 1024);
      gload16(Wt + (n0 + row) * EMB + kb + col, (char*)Bs + chunk * 1024);
    }
    __syncthreads();
    #pragma unroll
    for (int kk = 0; kk < 64; kk += 32) {
      short8 a[4], b[4];
      #pragma unroll
      for (int i = 0; i < 4; ++i)
        a[i] = *(const short8*)(As + (wr * 64 + i * 16 + ln) * 64 + kk + g * 8);
      #pragma unroll
      for (int j = 0; j < 4; ++j)
        b[j] = *(const short8*)(Bs + (wc * 64 + j * 16 + ln) * 64 + kk + g * 8);
      #pragma unroll
      for (int i = 0; i < 4; ++i)
        #pragma unroll
        for (int j = 0; j < 4; ++j)
          acc[i][j] = mfma16(a[i], b[j], acc[i][j]);
    }
    __syncthreads();
  }

  const int mb = m0 + wr * 64, nb = n0 + wc * 64;
  #pragma unroll
  for (int j = 0; j < 4; ++j) {
    const int n = nb + j * 16 + ln;
    const float bgain = bias[n];
    #pragma unroll
    for (int i = 0; i < 4; ++i) {
      #pragma unroll
      for (int e = 0; e < 4; ++e) {
        const int m = mb + i * 16 + 4 * g + e;
        out[m * EMB + n] = acc[i][j][e] + bgain;
      }
    }
  }
}

// ---------------------------------------------------------------------------
extern "C" void kernel_launch(void* const* d_in, const int* in_sizes, int n_in,
                              void* d_out, int out_size, void* d_ws, size_t ws_size,
                              hipStream_t stream) {
  const float* x  = (const float*)d_in[0];
  const float* Wq = (const float*)d_in[1];
  const float* bq = (const float*)d_in[2];
  const float* Wk = (const float*)d_in[3];
  const float* bk = (const float*)d_in[4];
  const float* Wv = (const float*)d_in[5];
  const float* bv = (const float*)d_in[6];
  const float* Wo = (const float*)d_in[7];
  const float* bo = (const float*)d_in[8];
  float* out = (float*)d_out;

  char* ws = (char*)d_ws;
  unsigned short* Xb  = (unsigned short*)(ws);              // 8 MB  [4096][1024]
  unsigned short* WqT = (unsigned short*)(ws + 8388608);    // 2 MB each [n][k]
  unsigned short* WkT = (unsigned short*)(ws + 10485760);
  unsigned short* WvT = (unsigned short*)(ws + 12582912);
  unsigned short* WoT = (unsigned short*)(ws + 14680064);
  unsigned short* Qb  = (unsigned short*)(ws + 16777216);   // 8 MB [b][h][s][d]
  unsigned short* Kb  = (unsigned short*)(ws + 25165824);   // 8 MB [b][h][s][d]
  unsigned short* Vtb = (unsigned short*)(ws + 33554432);   // 8 MB [b][h][d][s]
  unsigned short* Ao  = Xb;  // attention output reuses Xb (stream-ordered)

  hipLaunchKernelGGL(cvt_x_kernel, dim3(4096), dim3(256), 0, stream, x, Xb);
  hipLaunchKernelGGL(cvt_wt_kernel, dim3(32, 32), dim3(256), 0, stream, Wq, WqT);
  hipLaunchKernelGGL(cvt_wt_kernel, dim3(32, 32), dim3(256), 0, stream, Wk, WkT);
  hipLaunchKernelGGL(cvt_wt_kernel, dim3(32, 32), dim3(256), 0, stream, Wv, WvT);
  hipLaunchKernelGGL(cvt_wt_kernel, dim3(32, 32), dim3(256), 0, stream, Wo, WoT);
  hipLaunchKernelGGL(gemm_qkv_kernel, dim3(8, 32, 3), dim3(256), 0, stream,
                     Xb, WqT, WkT, WvT, bq, bk, bv, Qb, Kb, Vtb);
  hipLaunchKernelGGL(attn_kernel, dim3(32, 16, 2), dim3(256), 0, stream,
                     Qb, Kb, Vtb, Ao);
  hipLaunchKernelGGL(gemm_o_kernel, dim3(8, 32), dim3(256), 0, stream,
                     Ao, WoT, bo, out);
}

// Round 2
// 181.826 us; speedup vs baseline: 1.4061x; 1.4061x over previous
//
#include <hip/hip_runtime.h>

// ---------------------------------------------------------------------------
// Causal MHA block: QKV proj (bf16 MFMA) -> flash attention -> out proj.
// B=2, S=2048, E=1024, H=16, D=64.  All matmuls bf16 16x16x32 MFMA, fp32 acc.
// ---------------------------------------------------------------------------

#define EMB 1024
#define SEQ 2048
#define NB 2
#define NH 16
#define HD 64

// 0.125 (1/sqrt(64)) * log2(e): QK logits land in exp2 domain
#define QSCALE 0.18033688011112042f

typedef float f32x4 __attribute__((ext_vector_type(4)));
typedef float floatx4 __attribute__((ext_vector_type(4)));
typedef short short8 __attribute__((ext_vector_type(8)));
typedef __bf16 bf16x8 __attribute__((ext_vector_type(8)));
typedef unsigned short ushortx4 __attribute__((ext_vector_type(4)));
typedef unsigned int uintx4 __attribute__((ext_vector_type(4)));

__device__ __forceinline__ unsigned short f2bf(float f) {
  unsigned u = __builtin_bit_cast(unsigned, f);
  u += 0x7fffu + ((u >> 16) & 1u);   // round-to-nearest-even
  return (unsigned short)(u >> 16);
}

__device__ __forceinline__ unsigned pkbf(float lo, float hi) {
  return ((unsigned)f2bf(hi) << 16) | (unsigned)f2bf(lo);
}

__device__ __forceinline__ f32x4 mfma16(short8 a, short8 b, f32x4 c) {
  return __builtin_amdgcn_mfma_f32_16x16x32_bf16(
      __builtin_bit_cast(bf16x8, a), __builtin_bit_cast(bf16x8, b), c, 0, 0, 0);
}

// async global -> LDS, 16B per lane; lds dest is wave-uniform base + lane*16
__device__ __forceinline__ void gload16(const void* g, void* lds) {
  __builtin_amdgcn_global_load_lds(
      (const __attribute__((address_space(1))) unsigned int*)g,
      (__attribute__((address_space(3))) unsigned int*)lds, 16, 0, 0);
}

// ---------------------------------------------------------------------------
// fp32 -> bf16 convert (x)
// ---------------------------------------------------------------------------
__global__ __launch_bounds__(256) void cvt_x_kernel(
    const float* __restrict__ x, unsigned short* __restrict__ out) {
  const int idx = (blockIdx.x * 256 + threadIdx.x) * 4;
  floatx4 v = *(const floatx4*)(x + idx);
  ushortx4 o;
  #pragma unroll
  for (int i = 0; i < 4; ++i) o[i] = f2bf(v[i]);
  *(ushortx4*)(out + idx) = o;
}

// ---------------------------------------------------------------------------
// fp32 W[k][n] -> bf16 WT[n][k]  (convert + transpose, 32x32 LDS tile)
// ---------------------------------------------------------------------------
__global__ __launch_bounds__(256) void cvt_wt_kernel(
    const float* __restrict__ W, unsigned short* __restrict__ WT) {
  __shared__ unsigned short tile[32][33];
  const int k0 = blockIdx.x * 32, n0 = blockIdx.y * 32;
  const int t = threadIdx.x;
  const int r = t >> 3, c = (t & 7) * 4;
  floatx4 v = *(const floatx4*)(W + (k0 + r) * EMB + n0 + c);
  #pragma unroll
  for (int i = 0; i < 4; ++i) tile[r][c + i] = f2bf(v[i]);
  __syncthreads();
  ushortx4 o;
  #pragma unroll
  for (int i = 0; i < 4; ++i) o[i] = tile[c + i][r];
  *(ushortx4*)(WT + (n0 + r) * EMB + k0 + c) = o;
}

// ---------------------------------------------------------------------------
// GEMM: C[m][n] = Xb[m][k] * WT[n][k]^T + bias.  128x128 tile, BK=64, 4 waves.
// z=0 -> Q[b][h][s][d] (pre-scaled by QSCALE), z=1 -> K[b][h][s][d],
// z=2 -> Vt[b][h][d][s]
// ---------------------------------------------------------------------------
__global__ __launch_bounds__(256) void gemm_qkv_kernel(
    const unsigned short* __restrict__ Xb,
    const unsigned short* __restrict__ W0, const unsigned short* __restrict__ W1,
    const unsigned short* __restrict__ W2,
    const float* __restrict__ b0, const float* __restrict__ b1,
    const float* __restrict__ b2,
    unsigned short* __restrict__ Qo, unsigned short* __restrict__ Ko,
    unsigned short* __restrict__ Vo) {
  __shared__ __align__(16) unsigned short As[128 * 64];
  __shared__ __align__(16) unsigned short Bs[128 * 64];
  const int z = blockIdx.z;
  const unsigned short* Wt = (z == 0) ? W0 : ((z == 1) ? W1 : W2);
  const float* bias = (z == 0) ? b0 : ((z == 1) ? b1 : b2);
  const float osc = (z == 0) ? QSCALE : 1.0f;
  const int m0 = blockIdx.y * 128, n0 = blockIdx.x * 128;
  const int tid = threadIdx.x, l = tid & 63, w = tid >> 6;
  const int g = l >> 4, ln = l & 15;
  const int wr = w >> 1, wc = w & 1;

  f32x4 acc[4][4];
  #pragma unroll
  for (int i = 0; i < 4; ++i)
    #pragma unroll
    for (int j = 0; j < 4; ++j) acc[i][j] = (f32x4){0.f, 0.f, 0.f, 0.f};

  for (int kt = 0; kt < 16; ++kt) {
    const int kb = kt * 64;
    #pragma unroll
    for (int it = 0; it < 4; ++it) {
      const int chunk = w * 4 + it;          // 0..15, 1KB each
      const int lin = chunk * 64 + l;        // 16B-chunk index 0..1023
      const int row = lin >> 3, col = (lin & 7) * 8;
      gload16(Xb + (m0 + row) * EMB + kb + col, (char*)As + chunk * 1024);
      gload16(Wt + (n0 + row) * EMB + kb + col, (char*)Bs + chunk * 1024);
    }
    __syncthreads();
    #pragma unroll
    for (int kk = 0; kk < 64; kk += 32) {
      short8 a[4], b[4];
      #pragma unroll
      for (int i = 0; i < 4; ++i)
        a[i] = *(const short8*)(As + (wr * 64 + i * 16 + ln) * 64 + kk + g * 8);
      #pragma unroll
      for (int j = 0; j < 4; ++j)
        b[j] = *(const short8*)(Bs + (wc * 64 + j * 16 + ln) * 64 + kk + g * 8);
      #pragma unroll
      for (int i = 0; i < 4; ++i)
        #pragma unroll
        for (int j = 0; j < 4; ++j)
          acc[i][j] = mfma16(a[i], b[j], acc[i][j]);
    }
    __syncthreads();
  }

  const int mb = m0 + wr * 64, nb = n0 + wc * 64;
  #pragma unroll
  for (int j = 0; j < 4; ++j) {
    const int n = nb + j * 16 + ln;
    const float bgain = bias[n];
    const int h = n >> 6, d = n & 63;
    #pragma unroll
    for (int i = 0; i < 4; ++i) {
      const int mf = mb + i * 16 + 4 * g;    // first of 4 consecutive m rows
      const int bb = mf >> 11, ss = mf & 2047;
      if (z == 2) {
        ushortx4 o;
        #pragma unroll
        for (int e = 0; e < 4; ++e) o[e] = f2bf(acc[i][j][e] + bgain);
        *(ushortx4*)(Vo + ((bb * NH + h) * HD + d) * SEQ + ss) = o;
      } else {
        unsigned short* dst = (z == 0) ? Qo : Ko;
        const int base = ((bb * NH + h) * SEQ + ss) * HD + d;
        #pragma unroll
        for (int e = 0; e < 4; ++e)
          dst[base + e * HD] = f2bf((acc[i][j][e] + bgain) * osc);
      }
    }
  }
}

// ---------------------------------------------------------------------------
// Causal flash attention, swapped-operand structure.
// Block = 4 waves; each block processes TWO 64-row q-tiles (pair t, 31-t) for
// perfect load balance (33 KV-iterations per block).
// Per wave: 16 q-rows. QK^T computed swapped (mfma(K,Q)) so each lane owns one
// q-row slice -> softmax reduce = 2 shfl_xor; P packed to bf16 in-register and
// redistributed with 8 shfl per 32-k tile; PV swapped (mfma(Vt,P)) so m/l/acc
// rescale is thread-local and O stores are packed.
// K/V staged to LDS double-buffered via global_load_lds with XOR-swizzled
// global source (chunk ^= row&7); reads apply the same XOR -> conflict-free.
// 2-phase prefetch: raw s_barrier + counted s_waitcnt vmcnt(4).
// Q: pre-scaled by QSCALE in projection; softmax in exp2 domain.
// ---------------------------------------------------------------------------
__global__ __launch_bounds__(256) void attn_kernel(
    const unsigned short* __restrict__ Q, const unsigned short* __restrict__ K,
    const unsigned short* __restrict__ Vt, unsigned short* __restrict__ O) {
  __shared__ __align__(16) unsigned short Kt[2][64 * 64];
  __shared__ __align__(16) unsigned short Vl[2][64 * 64];
  const int tpair = blockIdx.x, h = blockIdx.y, b = blockIdx.z;
  const int tid = threadIdx.x, l = tid & 63, w = tid >> 6;
  const int g = l >> 4, ln = l & 15;
  const int bh = b * NH + h;
  const size_t baseQK = (size_t)bh * SEQ * HD;   // [s][d]
  const size_t baseV = (size_t)bh * HD * SEQ;    // [d][s]
  const int xr = ln & 7;                          // read-side swizzle xor
  const int srcA = ((g & 1) << 5) + ln;           // P-shuffle source lanes
  const int srcB = srcA + 16;
  const bool hi = (g >> 1) != 0;

  // staging lane constants: chunk = w*2+it, lin = chunk*64+l
  const int st_row0 = (w * 2 * 64 + l) >> 3, st_c0 = ((w * 2) * 64 + l) & 7;
  const int st_row1 = ((w * 2 + 1) * 64 + l) >> 3, st_c1 = ((w * 2 + 1) * 64 + l) & 7;
  const int st_csw0 = st_c0 ^ (st_row0 & 7);
  const int st_csw1 = st_c1 ^ (st_row1 & 7);

  #pragma unroll 1
  for (int pass = 0; pass < 2; ++pass) {
    const int qt = (pass == 0) ? (31 - tpair) : tpair;
    const int nkt = qt + 1;
    const int q0 = qt * 64, qw = q0 + w * 16;

    // stage kt=0 into buf 0 (4 gload_lds per wave)
    {
      gload16(K + baseQK + (size_t)(0 * 64 + st_row0) * HD + st_csw0 * 8,
              (char*)&Kt[0][0] + (w * 2) * 1024);
      gload16(Vt + baseV + (size_t)st_row0 * SEQ + 0 * 64 + st_csw0 * 8,
              (char*)&Vl[0][0] + (w * 2) * 1024);
      gload16(K + baseQK + (size_t)(0 * 64 + st_row1) * HD + st_csw1 * 8,
              (char*)&Kt[0][0] + (w * 2 + 1) * 1024);
      gload16(Vt + baseV + (size_t)st_row1 * SEQ + 0 * 64 + st_csw1 * 8,
              (char*)&Vl[0][0] + (w * 2 + 1) * 1024);
    }

    // Q fragments (B-operand: col = q = ln, contraction d)
    const int qrow = qw + ln;
    short8 qf0 = *(const short8*)(Q + baseQK + (size_t)qrow * HD + g * 8);
    short8 qf1 = *(const short8*)(Q + baseQK + (size_t)qrow * HD + 32 + g * 8);

    float m_run = -1e30f, l_run = 0.f;
    f32x4 acc[4];
    #pragma unroll
    for (int dj = 0; dj < 4; ++dj) acc[dj] = (f32x4){0.f, 0.f, 0.f, 0.f};

    #pragma unroll 1
    for (int kt = 0; kt < nkt; ++kt) {
      const int cur = kt & 1;
      const bool has_next = (kt + 1 < nkt);
      if (has_next) {  // prefetch next tile into other buffer
        const int nb = cur ^ 1;
        const int kn = kt + 1;
        gload16(K + baseQK + (size_t)(kn * 64 + st_row0) * HD + st_csw0 * 8,
                (char*)&Kt[nb][0] + (w * 2) * 1024);
        gload16(Vt + baseV + (size_t)st_row0 * SEQ + kn * 64 + st_csw0 * 8,
                (char*)&Vl[nb][0] + (w * 2) * 1024);
        gload16(K + baseQK + (size_t)(kn * 64 + st_row1) * HD + st_csw1 * 8,
                (char*)&Kt[nb][0] + (w * 2 + 1) * 1024);
        gload16(Vt + baseV + (size_t)st_row1 * SEQ + kn * 64 + st_csw1 * 8,
                (char*)&Vl[nb][0] + (w * 2 + 1) * 1024);
        asm volatile("s_waitcnt vmcnt(4)" ::: "memory");
      } else {
        asm volatile("s_waitcnt vmcnt(0)" ::: "memory");
      }
      __builtin_amdgcn_s_barrier();

      const bool diag = (kt == qt);
      const int jmax = diag ? w : 3;

      // QK^T swapped: sv[j][e] = S[q=qw+ln][k = kt*64 + j*16 + 4g+e]
      f32x4 sv[4];
      #pragma unroll
      for (int j = 0; j < 4; ++j)
        sv[j] = (f32x4){-1e30f, -1e30f, -1e30f, -1e30f};
      #pragma unroll
      for (int j = 0; j < 4; ++j) {
        if (j <= jmax) {
          f32x4 t = (f32x4){0.f, 0.f, 0.f, 0.f};
          short8 kf0 = *(const short8*)(
              &Kt[cur][(j * 16 + ln) * 64 + ((g ^ xr) * 8)]);
          t = mfma16(kf0, qf0, t);
          short8 kf1 = *(const short8*)(
              &Kt[cur][(j * 16 + ln) * 64 + (((4 + g) ^ xr) * 8)]);
          t = mfma16(kf1, qf1, t);
          if (diag && j == w) {
            #pragma unroll
            for (int e = 0; e < 4; ++e)
              sv[j][e] = (4 * g + e <= ln) ? t[e] : -1e30f;
          } else {
            sv[j] = t;
          }
        }
      }

      // online softmax (exp2 domain), per q-row = per ln
      float tm = -1e30f;
      #pragma unroll
      for (int j = 0; j < 4; ++j)
        #pragma unroll
        for (int e = 0; e < 4; ++e) tm = fmaxf(tm, sv[j][e]);
      tm = fmaxf(tm, __shfl_xor(tm, 16));
      tm = fmaxf(tm, __shfl_xor(tm, 32));
      const float nm = fmaxf(m_run, tm);
      const float al = exp2f(m_run - nm);
      m_run = nm;

      float p[4][4];
      float rs = 0.f;
      #pragma unroll
      for (int j = 0; j < 4; ++j)
        #pragma unroll
        for (int e = 0; e < 4; ++e) {
          p[j][e] = exp2f(sv[j][e] - nm);
          rs += p[j][e];
        }
      rs += __shfl_xor(rs, 16);
      rs += __shfl_xor(rs, 32);
      l_run = l_run * al + rs;
      #pragma unroll
      for (int dj = 0; dj < 4; ++dj) acc[dj] *= al;

      // pack P to bf16 pairs: pk[j][h] = {p[j][2h], p[j][2h+1]}
      unsigned pk[4][2];
      #pragma unroll
      for (int j = 0; j < 4; ++j) {
        pk[j][0] = pkbf(p[j][0], p[j][1]);
        pk[j][1] = pkbf(p[j][2], p[j][3]);
      }

      // build PV B-fragments: lane (g,ln) needs P[q=ln][k = ks*32 + 8g..8g+7]
      const int ksmax = (diag && w < 2) ? 1 : 2;
      short8 pf0, pf1;
      {
        unsigned a0 = __shfl(pk[0][0], srcA), a1 = __shfl(pk[0][1], srcA);
        unsigned a2 = __shfl(pk[0][0], srcB), a3 = __shfl(pk[0][1], srcB);
        unsigned b0 = __shfl(pk[1][0], srcA), b1 = __shfl(pk[1][1], srcA);
        unsigned b2 = __shfl(pk[1][0], srcB), b3 = __shfl(pk[1][1], srcB);
        uintx4 u;
        u[0] = hi ? b0 : a0; u[1] = hi ? b1 : a1;
        u[2] = hi ? b2 : a2; u[3] = hi ? b3 : a3;
        pf0 = __builtin_bit_cast(short8, u);
      }
      if (ksmax > 1) {
        unsigned a0 = __shfl(pk[2][0], srcA), a1 = __shfl(pk[2][1], srcA);
        unsigned a2 = __shfl(pk[2][0], srcB), a3 = __shfl(pk[2][1], srcB);
        unsigned b0 = __shfl(pk[3][0], srcA), b1 = __shfl(pk[3][1], srcA);
        unsigned b2 = __shfl(pk[3][0], srcB), b3 = __shfl(pk[3][1], srcB);
        uintx4 u;
        u[0] = hi ? b0 : a0; u[1] = hi ? b1 : a1;
        u[2] = hi ? b2 : a2; u[3] = hi ? b3 : a3;
        pf1 = __builtin_bit_cast(short8, u);
      }

      // PV swapped: acc rows = d (4g+e), cols = q (ln)
      #pragma unroll
      for (int dj = 0; dj < 4; ++dj) {
        short8 vb0 = *(const short8*)(
            &Vl[cur][(dj * 16 + ln) * 64 + ((g ^ xr) * 8)]);
        acc[dj] = mfma16(vb0, pf0, acc[dj]);
        if (ksmax > 1) {
          short8 vb1 = *(const short8*)(
              &Vl[cur][(dj * 16 + ln) * 64 + (((4 + g) ^ xr) * 8)]);
          acc[dj] = mfma16(vb1, pf1, acc[dj]);
        }
      }

      asm volatile("" ::: "memory");
      __builtin_amdgcn_s_barrier();
    }

    // epilogue: O[q = qw+ln][d = dj*16 + 4g+e], thread-local 1/l
    const float inv = 1.f / l_run;
    const size_t orow = ((size_t)b * SEQ + qw + ln) * EMB + h * HD;
    #pragma unroll
    for (int dj = 0; dj < 4; ++dj) {
      ushortx4 o;
      #pragma unroll
      for (int e = 0; e < 4; ++e) o[e] = f2bf(acc[dj][e] * inv);
      *(ushortx4*)(O + orow + dj * 16 + 4 * g) = o;
    }
  }
}

// ---------------------------------------------------------------------------
// Output projection: fp32 out = AttnOut(bf16) @ Wo + bo
// ---------------------------------------------------------------------------
__global__ __launch_bounds__(256) void gemm_o_kernel(
    const unsigned short* __restrict__ Ab, const unsigned short* __restrict__ Wt,
    const float* __restrict__ bias, float* __restrict__ out) {
  __shared__ __align__(16) unsigned short As[128 * 64];
  __shared__ __align__(16) unsigned short Bs[128 * 64];
  const int m0 = blockIdx.y * 128, n0 = blockIdx.x * 128;
  const int tid = threadIdx.x, l = tid & 63, w = tid >> 6;
  const int g = l >> 4, ln = l & 15;
  const int wr = w >> 1, wc = w & 1;

  f32x4 acc[4][4];
  #pragma unroll
  for (int i = 0; i < 4; ++i)
    #pragma unroll
    for (int j = 0; j < 4; ++j) acc[i][j] = (f32x4){0.f, 0.f, 0.f, 0.f};

  for (int kt = 0; kt < 16; ++kt) {
    const int kb = kt * 64;
    #pragma unroll
    for (int it = 0; it < 4; ++it) {
      const int chunk = w * 4 + it;
      const int lin = chunk * 64 + l;
      const int row = lin >> 3, col = (lin & 7) * 8;
      gload16(Ab + (m0 + row) * EMB + kb + col, (char*)As + chunk * 1024);
      gload16(Wt + (n0 + row) * EMB + kb + col, (char*)Bs + chunk * 1024);
    }
    __syncthreads();
    #pragma unroll
    for (int kk = 0; kk < 64; kk += 32) {
      short8 a[4], b[4];
      #pragma unroll
      for (int i = 0; i < 4; ++i)
        a[i] = *(const short8*)(As + (wr * 64 + i * 16 + ln) * 64 + kk + g * 8);
      #pragma unroll
      for (int j = 0; j < 4; ++j)
        b[j] = *(const short8*)(Bs + (wc * 64 + j * 16 + ln) * 64 + kk + g * 8);
      #pragma unroll
      for (int i = 0; i < 4; ++i)
        #pragma unroll
        for (int j = 0; j < 4; ++j)
          acc[i][j] = mfma16(a[i], b[j], acc[i][j]);
    }
    __syncthreads();
  }

  const int mb = m0 + wr * 64, nb = n0 + wc * 64;
  #pragma unroll
  for (int j = 0; j < 4; ++j) {
    const int n = nb + j * 16 + ln;
    const float bgain = bias[n];
    #pragma unroll
    for (int i = 0; i < 4; ++i) {
      #pragma unroll
      for (int e = 0; e < 4; ++e) {
        const int m = mb + i * 16 + 4 * g + e;
        out[m * EMB + n] = acc[i][j][e] + bgain;
      }
    }
  }
}

// ---------------------------------------------------------------------------
extern "C" void kernel_launch(void* const* d_in, const int* in_sizes, int n_in,
                              void* d_out, int out_size, void* d_ws, size_t ws_size,
                              hipStream_t stream) {
  const float* x  = (const float*)d_in[0];
  const float* Wq = (const float*)d_in[1];
  const float* bq = (const float*)d_in[2];
  const float* Wk = (const float*)d_in[3];
  const float* bk = (const float*)d_in[4];
  const float* Wv = (const float*)d_in[5];
  const float* bv = (const float*)d_in[6];
  const float* Wo = (const float*)d_in[7];
  const float* bo = (const float*)d_in[8];
  float* out = (float*)d_out;

  char* ws = (char*)d_ws;
  unsigned short* Xb  = (unsigned short*)(ws);              // 8 MB  [4096][1024]
  unsigned short* WqT = (unsigned short*)(ws + 8388608);    // 2 MB each [n][k]
  unsigned short* WkT = (unsigned short*)(ws + 10485760);
  unsigned short* WvT = (unsigned short*)(ws + 12582912);
  unsigned short* WoT = (unsigned short*)(ws + 14680064);
  unsigned short* Qb  = (unsigned short*)(ws + 16777216);   // 8 MB [b][h][s][d]
  unsigned short* Kb  = (unsigned short*)(ws + 25165824);   // 8 MB [b][h][s][d]
  unsigned short* Vtb = (unsigned short*)(ws + 33554432);   // 8 MB [b][h][d][s]
  unsigned short* Ao  = Xb;  // attention output reuses Xb (stream-ordered)

  hipLaunchKernelGGL(cvt_x_kernel, dim3(4096), dim3(256), 0, stream, x, Xb);
  hipLaunchKernelGGL(cvt_wt_kernel, dim3(32, 32), dim3(256), 0, stream, Wq, WqT);
  hipLaunchKernelGGL(cvt_wt_kernel, dim3(32, 32), dim3(256), 0, stream, Wk, WkT);
  hipLaunchKernelGGL(cvt_wt_kernel, dim3(32, 32), dim3(256), 0, stream, Wv, WvT);
  hipLaunchKernelGGL(cvt_wt_kernel, dim3(32, 32), dim3(256), 0, stream, Wo, WoT);
  hipLaunchKernelGGL(gemm_qkv_kernel, dim3(8, 32, 3), dim3(256), 0, stream,
                     Xb, WqT, WkT, WvT, bq, bk, bv, Qb, Kb, Vtb);
  hipLaunchKernelGGL(attn_kernel, dim3(16, 16, 2), dim3(256), 0, stream,
                     Qb, Kb, Vtb, Ao);
  hipLaunchKernelGGL(gemm_o_kernel, dim3(8, 32), dim3(256), 0, stream,
                     Ao, WoT, bo, out);
}

// Round 4
// 173.979 us; speedup vs baseline: 1.4695x; 1.0451x over previous
//
#include <hip/hip_runtime.h>

// ---------------------------------------------------------------------------
// Causal MHA block: QKV proj (bf16 MFMA) -> flash attention -> out proj.
// B=2, S=2048, E=1024, H=16, D=64.  All matmuls bf16 16x16x32 MFMA, fp32 acc.
// ---------------------------------------------------------------------------

#define EMB 1024
#define SEQ 2048
#define NB 2
#define NH 16
#define HD 64

// 0.125 (1/sqrt(64)) * log2(e): QK logits land in exp2 domain
#define QSCALE 0.18033688011112042f

typedef float f32x4 __attribute__((ext_vector_type(4)));
typedef float floatx4 __attribute__((ext_vector_type(4)));
typedef short short8 __attribute__((ext_vector_type(8)));
typedef __bf16 bf16x8 __attribute__((ext_vector_type(8)));
typedef __bf16 bf16x2 __attribute__((ext_vector_type(2)));
typedef unsigned short ushortx4 __attribute__((ext_vector_type(4)));
typedef unsigned int uintx4 __attribute__((ext_vector_type(4)));

// native f32->bf16 (RNE, compiler emits v_cvt_pk_bf16_f32 for pairs)
__device__ __forceinline__ unsigned short bf16u(float f) {
  __bf16 h = (__bf16)f;
  return __builtin_bit_cast(unsigned short, h);
}

__device__ __forceinline__ unsigned pkbf(float lo, float hi) {
  bf16x2 v;
  v[0] = (__bf16)lo;
  v[1] = (__bf16)hi;
  return __builtin_bit_cast(unsigned, v);
}

__device__ __forceinline__ f32x4 mfma16(short8 a, short8 b, f32x4 c) {
  return __builtin_amdgcn_mfma_f32_16x16x32_bf16(
      __builtin_bit_cast(bf16x8, a), __builtin_bit_cast(bf16x8, b), c, 0, 0, 0);
}

// async global -> LDS, 16B per lane; lds dest is wave-uniform base + lane*16
__device__ __forceinline__ void gload16(const void* g, void* lds) {
  __builtin_amdgcn_global_load_lds(
      (const __attribute__((address_space(1))) unsigned int*)g,
      (__attribute__((address_space(3))) unsigned int*)lds, 16, 0, 0);
}

// ---------------------------------------------------------------------------
// fp32 -> bf16 convert (x)
// ---------------------------------------------------------------------------
__global__ __launch_bounds__(256) void cvt_x_kernel(
    const float* __restrict__ x, unsigned short* __restrict__ out) {
  const int idx = (blockIdx.x * 256 + threadIdx.x) * 4;
  floatx4 v = *(const floatx4*)(x + idx);
  ushortx4 o;
  #pragma unroll
  for (int i = 0; i < 4; ++i) o[i] = bf16u(v[i]);
  *(ushortx4*)(out + idx) = o;
}

// ---------------------------------------------------------------------------
// fp32 W[k][n] -> bf16 WT[n][k] for all four weight matrices (z selects)
// ---------------------------------------------------------------------------
__global__ __launch_bounds__(256) void cvt_w4_kernel(
    const float* __restrict__ W0, const float* __restrict__ W1,
    const float* __restrict__ W2, const float* __restrict__ W3,
    unsigned short* __restrict__ T0, unsigned short* __restrict__ T1,
    unsigned short* __restrict__ T2, unsigned short* __restrict__ T3) {
  __shared__ unsigned short tile[32][33];
  const int z = blockIdx.z;
  const float* W = (z == 0) ? W0 : (z == 1) ? W1 : (z == 2) ? W2 : W3;
  unsigned short* WT = (z == 0) ? T0 : (z == 1) ? T1 : (z == 2) ? T2 : T3;
  const int k0 = blockIdx.x * 32, n0 = blockIdx.y * 32;
  const int t = threadIdx.x;
  const int r = t >> 3, c = (t & 7) * 4;
  floatx4 v = *(const floatx4*)(W + (k0 + r) * EMB + n0 + c);
  #pragma unroll
  for (int i = 0; i < 4; ++i) tile[r][c + i] = bf16u(v[i]);
  __syncthreads();
  ushortx4 o;
  #pragma unroll
  for (int i = 0; i < 4; ++i) o[i] = tile[c + i][r];
  *(ushortx4*)(WT + (n0 + r) * EMB + k0 + c) = o;
}

// shared k-loop body for the 128x128 GEMMs; OP1's tile index lands on the
// accumulator reg axis (4g+e), OP2's on the lane-col axis (ln).
#define GEMM_KLOOP(OP1, OP2)                                                 \
    for (int kk = 0; kk < 64; kk += 32) {                                    \
      short8 a[4], b[4];                                                     \
      _Pragma("unroll")                                                      \
      for (int i = 0; i < 4; ++i)                                            \
        a[i] = *(const short8*)(As + (wr * 64 + i * 16 + ln) * 64 + kk + g * 8); \
      _Pragma("unroll")                                                      \
      for (int j = 0; j < 4; ++j)                                            \
        b[j] = *(const short8*)(Bs + (wc * 64 + j * 16 + ln) * 64 + kk + g * 8); \
      _Pragma("unroll")                                                      \
      for (int i = 0; i < 4; ++i)                                            \
        _Pragma("unroll")                                                    \
        for (int j = 0; j < 4; ++j)                                          \
          acc[i][j] = mfma16(OP1, OP2, acc[i][j]);                           \
    }

// ---------------------------------------------------------------------------
// GEMM: C[m][n] = Xb[m][k] * WT[n][k]^T + bias.  128x128 tile, BK=64, 4 waves.
// z=0 -> Q[b][h][s][d] (pre-scaled by QSCALE), z=1 -> K[b][h][s][d]:
//   operand-swapped MFMA so regs walk d -> packed ushortx4 stores.
// z=2 -> Vt[b][h][d][s]: normal order so regs walk s -> packed stores.
// ---------------------------------------------------------------------------
__global__ __launch_bounds__(256) void gemm_qkv_kernel(
    const unsigned short* __restrict__ Xb,
    const unsigned short* __restrict__ W0, const unsigned short* __restrict__ W1,
    const unsigned short* __restrict__ W2,
    const float* __restrict__ b0, const float* __restrict__ b1,
    const float* __restrict__ b2,
    unsigned short* __restrict__ Qo, unsigned short* __restrict__ Ko,
    unsigned short* __restrict__ Vo) {
  __shared__ __align__(16) unsigned short As[128 * 64];
  __shared__ __align__(16) unsigned short Bs[128 * 64];
  const int z = blockIdx.z;
  const unsigned short* Wt = (z == 0) ? W0 : ((z == 1) ? W1 : W2);
  const float* bias = (z == 0) ? b0 : ((z == 1) ? b1 : b2);
  const bool sw = (z != 2);
  const int m0 = blockIdx.y * 128, n0 = blockIdx.x * 128;
  const int tid = threadIdx.x, l = tid & 63, w = tid >> 6;
  const int g = l >> 4, ln = l & 15;
  const int wr = w >> 1, wc = w & 1;

  f32x4 acc[4][4];
  #pragma unroll
  for (int i = 0; i < 4; ++i)
    #pragma unroll
    for (int j = 0; j < 4; ++j) acc[i][j] = (f32x4){0.f, 0.f, 0.f, 0.f};

  for (int kt = 0; kt < 16; ++kt) {
    const int kb = kt * 64;
    #pragma unroll
    for (int it = 0; it < 4; ++it) {
      const int chunk = w * 4 + it;          // 0..15, 1KB each
      const int lin = chunk * 64 + l;        // 16B-chunk index 0..1023
      const int row = lin >> 3, col = (lin & 7) * 8;
      gload16(Xb + (m0 + row) * EMB + kb + col, (char*)As + chunk * 1024);
      gload16(Wt + (n0 + row) * EMB + kb + col, (char*)Bs + chunk * 1024);
    }
    __syncthreads();
    if (sw) {
      GEMM_KLOOP(b[j], a[i])
    } else {
      GEMM_KLOOP(a[i], b[j])
    }
    __syncthreads();
  }

  const int mb = m0 + wr * 64, nb = n0 + wc * 64;
  if (sw) {
    // regs walk n (=d): packed stores along d for Q/K [b][h][s][d]
    unsigned short* dst = (z == 0) ? Qo : Ko;
    const float osc = (z == 0) ? QSCALE : 1.0f;
    #pragma unroll
    for (int j = 0; j < 4; ++j) {
      const int n = nb + j * 16 + 4 * g;
      floatx4 bv_ = *(const floatx4*)(bias + n);
      const int h = n >> 6, d = n & 63;
      #pragma unroll
      for (int i = 0; i < 4; ++i) {
        const int m = mb + i * 16 + ln;      // global s-row
        const int bb = m >> 11, ss = m & 2047;
        ushortx4 o;
        #pragma unroll
        for (int e = 0; e < 4; ++e) o[e] = bf16u((acc[i][j][e] + bv_[e]) * osc);
        *(ushortx4*)(dst + ((bb * NH + h) * SEQ + ss) * HD + d) = o;
      }
    }
  } else {
    // regs walk m (=s): packed stores along s for Vt [b][h][d][s]
    #pragma unroll
    for (int j = 0; j < 4; ++j) {
      const int n = nb + j * 16 + ln;
      const float bgain = bias[n];
      const int h = n >> 6, d = n & 63;
      #pragma unroll
      for (int i = 0; i < 4; ++i) {
        const int mf = mb + i * 16 + 4 * g;
        const int bb = mf >> 11, ss = mf & 2047;
        ushortx4 o;
        #pragma unroll
        for (int e = 0; e < 4; ++e) o[e] = bf16u(acc[i][j][e] + bgain);
        *(ushortx4*)(Vo + ((bb * NH + h) * HD + d) * SEQ + ss) = o;
      }
    }
  }
}

// ---------------------------------------------------------------------------
// Causal flash attention, swapped-operand structure — round-2 value path
// (always-rescale online softmax, f32 shuffle row-sum) + setprio + native
// cvt_pk packing.
// ---------------------------------------------------------------------------
__global__ __launch_bounds__(256) void attn_kernel(
    const unsigned short* __restrict__ Q, const unsigned short* __restrict__ K,
    const unsigned short* __restrict__ Vt, unsigned short* __restrict__ O) {
  __shared__ __align__(16) unsigned short Kt[2][64 * 64];
  __shared__ __align__(16) unsigned short Vl[2][64 * 64];
  const int tpair = blockIdx.x, h = blockIdx.y, b = blockIdx.z;
  const int tid = threadIdx.x, l = tid & 63, w = tid >> 6;
  const int g = l >> 4, ln = l & 15;
  const int bh = b * NH + h;
  const size_t baseQK = (size_t)bh * SEQ * HD;   // [s][d]
  const size_t baseV = (size_t)bh * HD * SEQ;    // [d][s]
  const int xr = ln & 7;                          // read-side swizzle xor
  const int srcA = ((g & 1) << 5) + ln;           // P-shuffle source lanes
  const int srcB = srcA + 16;
  const bool hi = (g >> 1) != 0;

  // staging lane constants: chunk = w*2+it, lin = chunk*64+l
  const int st_row0 = (w * 2 * 64 + l) >> 3, st_c0 = ((w * 2) * 64 + l) & 7;
  const int st_row1 = ((w * 2 + 1) * 64 + l) >> 3, st_c1 = ((w * 2 + 1) * 64 + l) & 7;
  const int st_csw0 = st_c0 ^ (st_row0 & 7);
  const int st_csw1 = st_c1 ^ (st_row1 & 7);

  #pragma unroll 1
  for (int pass = 0; pass < 2; ++pass) {
    const int qt = (pass == 0) ? (31 - tpair) : tpair;
    const int nkt = qt + 1;
    const int q0 = qt * 64, qw = q0 + w * 16;

    // stage kt=0 into buf 0 (4 gload_lds per wave)
    {
      gload16(K + baseQK + (size_t)(0 * 64 + st_row0) * HD + st_csw0 * 8,
              (char*)&Kt[0][0] + (w * 2) * 1024);
      gload16(Vt + baseV + (size_t)st_row0 * SEQ + 0 * 64 + st_csw0 * 8,
              (char*)&Vl[0][0] + (w * 2) * 1024);
      gload16(K + baseQK + (size_t)(0 * 64 + st_row1) * HD + st_csw1 * 8,
              (char*)&Kt[0][0] + (w * 2 + 1) * 1024);
      gload16(Vt + baseV + (size_t)st_row1 * SEQ + 0 * 64 + st_csw1 * 8,
              (char*)&Vl[0][0] + (w * 2 + 1) * 1024);
    }

    // Q fragments (B-operand: col = q = ln, contraction d)
    const int qrow = qw + ln;
    short8 qf0 = *(const short8*)(Q + baseQK + (size_t)qrow * HD + g * 8);
    short8 qf1 = *(const short8*)(Q + baseQK + (size_t)qrow * HD + 32 + g * 8);

    float m_run = -1e30f, l_run = 0.f;
    f32x4 acc[4];
    #pragma unroll
    for (int dj = 0; dj < 4; ++dj) acc[dj] = (f32x4){0.f, 0.f, 0.f, 0.f};

    #pragma unroll 1
    for (int kt = 0; kt < nkt; ++kt) {
      const int cur = kt & 1;
      const bool has_next = (kt + 1 < nkt);
      if (has_next) {  // prefetch next tile into other buffer
        const int nxt = cur ^ 1;
        const int kn = kt + 1;
        gload16(K + baseQK + (size_t)(kn * 64 + st_row0) * HD + st_csw0 * 8,
                (char*)&Kt[nxt][0] + (w * 2) * 1024);
        gload16(Vt + baseV + (size_t)st_row0 * SEQ + kn * 64 + st_csw0 * 8,
                (char*)&Vl[nxt][0] + (w * 2) * 1024);
        gload16(K + baseQK + (size_t)(kn * 64 + st_row1) * HD + st_csw1 * 8,
                (char*)&Kt[nxt][0] + (w * 2 + 1) * 1024);
        gload16(Vt + baseV + (size_t)st_row1 * SEQ + kn * 64 + st_csw1 * 8,
                (char*)&Vl[nxt][0] + (w * 2 + 1) * 1024);
        asm volatile("s_waitcnt vmcnt(4)" ::: "memory");
      } else {
        asm volatile("s_waitcnt vmcnt(0)" ::: "memory");
      }
      __builtin_amdgcn_s_barrier();

      const bool diag = (kt == qt);
      const int jmax = diag ? w : 3;

      // QK^T swapped: sv[j][e] = S[q=qw+ln][k = kt*64 + j*16 + 4g+e]
      f32x4 sv[4];
      #pragma unroll
      for (int j = 0; j < 4; ++j)
        sv[j] = (f32x4){-1e30f, -1e30f, -1e30f, -1e30f};
      __builtin_amdgcn_s_setprio(1);
      #pragma unroll
      for (int j = 0; j < 4; ++j) {
        if (j <= jmax) {
          f32x4 t = (f32x4){0.f, 0.f, 0.f, 0.f};
          short8 kf0 = *(const short8*)(
              &Kt[cur][(j * 16 + ln) * 64 + ((g ^ xr) * 8)]);
          t = mfma16(kf0, qf0, t);
          short8 kf1 = *(const short8*)(
              &Kt[cur][(j * 16 + ln) * 64 + (((4 + g) ^ xr) * 8)]);
          t = mfma16(kf1, qf1, t);
          if (diag && j == w) {
            #pragma unroll
            for (int e = 0; e < 4; ++e)
              sv[j][e] = (4 * g + e <= ln) ? t[e] : -1e30f;
          } else {
            sv[j] = t;
          }
        }
      }
      __builtin_amdgcn_s_setprio(0);

      // online softmax (exp2 domain), per q-row = per ln
      float tm = -1e30f;
      #pragma unroll
      for (int j = 0; j < 4; ++j)
        #pragma unroll
        for (int e = 0; e < 4; ++e) tm = fmaxf(tm, sv[j][e]);
      tm = fmaxf(tm, __shfl_xor(tm, 16));
      tm = fmaxf(tm, __shfl_xor(tm, 32));
      const float nm = fmaxf(m_run, tm);
      const float al = exp2f(m_run - nm);
      m_run = nm;

      float p[4][4];
      float rs = 0.f;
      #pragma unroll
      for (int j = 0; j < 4; ++j)
        #pragma unroll
        for (int e = 0; e < 4; ++e) {
          p[j][e] = exp2f(sv[j][e] - nm);
          rs += p[j][e];
        }
      rs += __shfl_xor(rs, 16);
      rs += __shfl_xor(rs, 32);
      l_run = l_run * al + rs;
      #pragma unroll
      for (int dj = 0; dj < 4; ++dj) acc[dj] *= al;

      // pack P to bf16 pairs: pk[j][c] = {p[j][2c], p[j][2c+1]}
      unsigned pk[4][2];
      #pragma unroll
      for (int j = 0; j < 4; ++j) {
        pk[j][0] = pkbf(p[j][0], p[j][1]);
        pk[j][1] = pkbf(p[j][2], p[j][3]);
      }

      // build PV B-fragments: lane (g,ln) needs P[q=ln][k = ks*32 + 8g..8g+7]
      const int ksmax = (diag && w < 2) ? 1 : 2;
      short8 pf0, pf1;
      {
        unsigned a0 = __shfl(pk[0][0], srcA), a1 = __shfl(pk[0][1], srcA);
        unsigned a2 = __shfl(pk[0][0], srcB), a3 = __shfl(pk[0][1], srcB);
        unsigned b0 = __shfl(pk[1][0], srcA), b1 = __shfl(pk[1][1], srcA);
        unsigned b2 = __shfl(pk[1][0], srcB), b3 = __shfl(pk[1][1], srcB);
        uintx4 u;
        u[0] = hi ? b0 : a0; u[1] = hi ? b1 : a1;
        u[2] = hi ? b2 : a2; u[3] = hi ? b3 : a3;
        pf0 = __builtin_bit_cast(short8, u);
      }
      if (ksmax > 1) {
        unsigned a0 = __shfl(pk[2][0], srcA), a1 = __shfl(pk[2][1], srcA);
        unsigned a2 = __shfl(pk[2][0], srcB), a3 = __shfl(pk[2][1], srcB);
        unsigned b0 = __shfl(pk[3][0], srcA), b1 = __shfl(pk[3][1], srcA);
        unsigned b2 = __shfl(pk[3][0], srcB), b3 = __shfl(pk[3][1], srcB);
        uintx4 u;
        u[0] = hi ? b0 : a0; u[1] = hi ? b1 : a1;
        u[2] = hi ? b2 : a2; u[3] = hi ? b3 : a3;
        pf1 = __builtin_bit_cast(short8, u);
      }

      // PV swapped: acc rows = d (4g+e), cols = q (ln)
      __builtin_amdgcn_s_setprio(1);
      #pragma unroll
      for (int dj = 0; dj < 4; ++dj) {
        short8 vb0 = *(const short8*)(
            &Vl[cur][(dj * 16 + ln) * 64 + ((g ^ xr) * 8)]);
        acc[dj] = mfma16(vb0, pf0, acc[dj]);
        if (ksmax > 1) {
          short8 vb1 = *(const short8*)(
              &Vl[cur][(dj * 16 + ln) * 64 + (((4 + g) ^ xr) * 8)]);
          acc[dj] = mfma16(vb1, pf1, acc[dj]);
        }
      }
      __builtin_amdgcn_s_setprio(0);

      asm volatile("" ::: "memory");
      __builtin_amdgcn_s_barrier();
    }

    // epilogue: O[q = qw+ln][d = dj*16 + 4g+e], thread-local 1/l
    const float inv = 1.f / l_run;
    const size_t orow = ((size_t)b * SEQ + qw + ln) * EMB + h * HD;
    #pragma unroll
    for (int dj = 0; dj < 4; ++dj) {
      ushortx4 o;
      #pragma unroll
      for (int e = 0; e < 4; ++e) o[e] = bf16u(acc[dj][e] * inv);
      *(ushortx4*)(O + orow + dj * 16 + 4 * g) = o;
    }
  }
}

// ---------------------------------------------------------------------------
// Output projection: fp32 out = AttnOut(bf16) @ Wo + bo.
// Operand-swapped so regs walk n -> float4 stores.
// ---------------------------------------------------------------------------
__global__ __launch_bounds__(256) void gemm_o_kernel(
    const unsigned short* __restrict__ Ab, const unsigned short* __restrict__ Wt,
    const float* __restrict__ bias, float* __restrict__ out) {
  __shared__ __align__(16) unsigned short As[128 * 64];
  __shared__ __align__(16) unsigned short Bs[128 * 64];
  const int m0 = blockIdx.y * 128, n0 = blockIdx.x * 128;
  const int tid = threadIdx.x, l = tid & 63, w = tid >> 6;
  const int g = l >> 4, ln = l & 15;
  const int wr = w >> 1, wc = w & 1;

  f32x4 acc[4][4];
  #pragma unroll
  for (int i = 0; i < 4; ++i)
    #pragma unroll
    for (int j = 0; j < 4; ++j) acc[i][j] = (f32x4){0.f, 0.f, 0.f, 0.f};

  for (int kt = 0; kt < 16; ++kt) {
    const int kb = kt * 64;
    #pragma unroll
    for (int it = 0; it < 4; ++it) {
      const int chunk = w * 4 + it;
      const int lin = chunk * 64 + l;
      const int row = lin >> 3, col = (lin & 7) * 8;
      gload16(Ab + (m0 + row) * EMB + kb + col, (char*)As + chunk * 1024);
      gload16(Wt + (n0 + row) * EMB + kb + col, (char*)Bs + chunk * 1024);
    }
    __syncthreads();
    GEMM_KLOOP(b[j], a[i])
    __syncthreads();
  }

  const int mb = m0 + wr * 64, nb = n0 + wc * 64;
  #pragma unroll
  for (int j = 0; j < 4; ++j) {
    const int n = nb + j * 16 + 4 * g;
    floatx4 bv_ = *(const floatx4*)(bias + n);
    #pragma unroll
    for (int i = 0; i < 4; ++i) {
      const int m = mb + i * 16 + ln;
      floatx4 o = acc[i][j] + bv_;
      *(floatx4*)(out + (size_t)m * EMB + n) = o;
    }
  }
}

// ---------------------------------------------------------------------------
extern "C" void kernel_launch(void* const* d_in, const int* in_sizes, int n_in,
                              void* d_out, int out_size, void* d_ws, size_t ws_size,
                              hipStream_t stream) {
  const float* x  = (const float*)d_in[0];
  const float* Wq = (const float*)d_in[1];
  const float* bq = (const float*)d_in[2];
  const float* Wk = (const float*)d_in[3];
  const float* bk = (const float*)d_in[4];
  const float* Wv = (const float*)d_in[5];
  const float* bv = (const float*)d_in[6];
  const float* Wo = (const float*)d_in[7];
  const float* bo = (const float*)d_in[8];
  float* out = (float*)d_out;

  char* ws = (char*)d_ws;
  unsigned short* Xb  = (unsigned short*)(ws);              // 8 MB  [4096][1024]
  unsigned short* WqT = (unsigned short*)(ws + 8388608);    // 2 MB each [n][k]
  unsigned short* WkT = (unsigned short*)(ws + 10485760);
  unsigned short* WvT = (unsigned short*)(ws + 12582912);
  unsigned short* WoT = (unsigned short*)(ws + 14680064);
  unsigned short* Qb  = (unsigned short*)(ws + 16777216);   // 8 MB [b][h][s][d]
  unsigned short* Kb  = (unsigned short*)(ws + 25165824);   // 8 MB [b][h][s][d]
  unsigned short* Vtb = (unsigned short*)(ws + 33554432);   // 8 MB [b][h][d][s]
  unsigned short* Ao  = Xb;  // attention output reuses Xb (stream-ordered)

  hipLaunchKernelGGL(cvt_x_kernel, dim3(4096), dim3(256), 0, stream, x, Xb);
  hipLaunchKernelGGL(cvt_w4_kernel, dim3(32, 32, 4), dim3(256), 0, stream,
                     Wq, Wk, Wv, Wo, WqT, WkT, WvT, WoT);
  hipLaunchKernelGGL(gemm_qkv_kernel, dim3(8, 32, 3), dim3(256), 0, stream,
                     Xb, WqT, WkT, WvT, bq, bk, bv, Qb, Kb, Vtb);
  hipLaunchKernelGGL(attn_kernel, dim3(16, 16, 2), dim3(256), 0, stream,
                     Qb, Kb, Vtb, Ao);
  hipLaunchKernelGGL(gemm_o_kernel, dim3(8, 32), dim3(256), 0, stream,
                     Ao, WoT, bo, out);
}